// Round 1
// baseline (2272.577 us; speedup 1.0000x reference)
//
#include <hip/hip_runtime.h>
#include <math.h>

#define DEV __device__ __forceinline__

using v8s = __attribute__((ext_vector_type(8))) short;   // 8 bf16 (4 VGPRs)
using v4f = __attribute__((ext_vector_type(4))) float;   // 4 fp32 acc

// ---------- bf16 helpers (RNE) ----------
DEV short f2bf(float f) {
    unsigned u = __float_as_uint(f);
    unsigned r = (u + 0x7fffu + ((u >> 16) & 1u)) >> 16;
    return (short)(unsigned short)r;
}
DEV float bf2f(short s) {
    return __uint_as_float(((unsigned)(unsigned short)s) << 16);
}
DEV unsigned pack2(short a, short b) {
    return ((unsigned)(unsigned short)a) | (((unsigned)(unsigned short)b) << 16);
}

// ---------- block reductions (256 threads = 4 waves) ----------
DEV float block_sum256(float v, float* red) {
    __syncthreads();
#pragma unroll
    for (int o = 32; o >= 1; o >>= 1) v += __shfl_down(v, o, 64);
    if ((threadIdx.x & 63) == 0) red[threadIdx.x >> 6] = v;
    __syncthreads();
    return red[0] + red[1] + red[2] + red[3];
}
DEV float block_max256(float v, float* red) {
    __syncthreads();
#pragma unroll
    for (int o = 32; o >= 1; o >>= 1) v = fmaxf(v, __shfl_down(v, o, 64));
    if ((threadIdx.x & 63) == 0) red[threadIdx.x >> 6] = v;
    __syncthreads();
    return fmaxf(fmaxf(red[0], red[1]), fmaxf(red[2], red[3]));
}

// ---------------- model constants ----------------
// V=32000 D=1024 L=2 H=16 KVH=4 HD=64 E=8 FF=2048 K=2 B=2 S=1024

// ---------------- generic GEMM ----------------
// C[M,N] = A[M,K](bf16 hi/lo planes) * B[N,K]^T (fp32, converted to bf16(+lo) in staging)
struct GemmP {
    const short* Ah; const short* Al;
    const float* B;
    float* C; short* Ch; short* Cl;
    const int* cnt; const int* prefix; const int* ltok; const int* lrow;
    long strideAz, strideBz, strideCz;
    int M, N, K, lda, ldb, ldc;
    float alpha;
    int outMode;    // 0 store f32, 1 C += alpha*acc, 2 split-bf16 store (Ch/Cl)
    int gqaB;       // B z-offset uses GQA mapping (z=b*16+h -> b*4+h/4)
    int attnC;      // C offset = b*S*D + h*HD (attn output layout)
    int grouped;    // 0 none; 1 gather A rows by token list, C rows at prefix; 2 A rows at prefix, C rows scattered by lrow
    int causalSkip; // skip blocks with nt > mt
    int causalK;    // limit K loop to (mt+1)*128
};

template<bool SPLIT>
__global__ __launch_bounds__(256) void gemm_bt(GemmP p) {
    const int tid = threadIdx.x;
    const int z = blockIdx.z, mt = blockIdx.y, nt = blockIdx.x;
    if (p.causalSkip && nt > mt) return;

    int Mz = p.M;
    const int* ltokz = nullptr; const int* lrowz = nullptr; int pz = 0;
    if (p.grouped) {
        Mz = p.cnt[z]; pz = p.prefix[z];
        ltokz = p.ltok + z * 2048; lrowz = p.lrow + z * 2048;
    }
    if (mt * 128 >= Mz) return;

    long aOff = (long)z * p.strideAz;
    long bOff, cOff;
    if (p.gqaB) { int b = z >> 4, h = z & 15; bOff = (long)(b * 4 + (h >> 2)) * p.strideBz; }
    else bOff = (long)z * p.strideBz;
    if (p.attnC) { int b = z >> 4, h = z & 15; cOff = (long)b * 1048576 + h * 64; }
    else cOff = (long)z * p.strideCz;

    extern __shared__ char smem[];
    short* Ahs = (short*)smem;          // [4][128][8]
    short* Bhs = Ahs + 4096;
    short* Als = Bhs + 4096;            // SPLIT only
    short* Bls = Als + 4096;

    const int lane = tid & 63, w = tid >> 6;
    const int lr = lane & 15, lg = lane >> 4;
    const int wr = w >> 1, wc = w & 1;

    v4f acc[4][4];
#pragma unroll
    for (int i = 0; i < 4; ++i)
#pragma unroll
        for (int j = 0; j < 4; ++j) { acc[i][j][0] = 0.f; acc[i][j][1] = 0.f; acc[i][j][2] = 0.f; acc[i][j][3] = 0.f; }

    const int srow = tid >> 1;          // 0..127
    const int sseg = tid & 1;           // which 16-elem half of BK=32

    int am = mt * 128 + srow; if (am >= Mz) am = Mz - 1;
    long arowoff;
    if (p.grouped == 1)      arowoff = (long)ltokz[am] * p.lda;
    else if (p.grouped == 2) arowoff = (long)(pz + am) * p.lda;
    else                     arowoff = aOff + (long)am * p.lda;
    int bn = nt * 128 + srow; if (bn >= p.N) bn = p.N - 1;
    long browoff = bOff + (long)bn * p.ldb;

    const int kEnd = p.causalK ? min(p.K, (mt + 1) * 128) : p.K;

    for (int k0 = 0; k0 < kEnd; k0 += 32) {
        __syncthreads();
        const int kb = k0 + sseg * 16;
        const int kg = sseg * 2;
        // ---- stage A (bf16 planes) ----
        {
            const uint4* src = (const uint4*)(p.Ah + arowoff + kb);
            uint4 h0 = src[0], h1 = src[1];
            *(uint4*)(Ahs + (kg * 128 + srow) * 8) = h0;
            *(uint4*)(Ahs + ((kg + 1) * 128 + srow) * 8) = h1;
            if (SPLIT) {
                const uint4* sl = (const uint4*)(p.Al + arowoff + kb);
                uint4 l0 = sl[0], l1 = sl[1];
                *(uint4*)(Als + (kg * 128 + srow) * 8) = l0;
                *(uint4*)(Als + ((kg + 1) * 128 + srow) * 8) = l1;
            }
        }
        // ---- stage B (fp32 -> bf16 hi(+lo)) ----
        {
            const float* bp = p.B + browoff + kb;
#pragma unroll
            for (int q = 0; q < 2; ++q) {
                float4 fa = *(const float4*)(bp + q * 8);
                float4 fb = *(const float4*)(bp + q * 8 + 4);
                short h0 = f2bf(fa.x), h1 = f2bf(fa.y), h2 = f2bf(fa.z), h3 = f2bf(fa.w);
                short h4 = f2bf(fb.x), h5 = f2bf(fb.y), h6 = f2bf(fb.z), h7 = f2bf(fb.w);
                uint4 hp = make_uint4(pack2(h0, h1), pack2(h2, h3), pack2(h4, h5), pack2(h6, h7));
                *(uint4*)(Bhs + ((kg + q) * 128 + srow) * 8) = hp;
                if (SPLIT) {
                    short l0 = f2bf(fa.x - bf2f(h0)), l1 = f2bf(fa.y - bf2f(h1));
                    short l2 = f2bf(fa.z - bf2f(h2)), l3 = f2bf(fa.w - bf2f(h3));
                    short l4 = f2bf(fb.x - bf2f(h4)), l5 = f2bf(fb.y - bf2f(h5));
                    short l6 = f2bf(fb.z - bf2f(h6)), l7 = f2bf(fb.w - bf2f(h7));
                    uint4 lp = make_uint4(pack2(l0, l1), pack2(l2, l3), pack2(l4, l5), pack2(l6, l7));
                    *(uint4*)(Bls + ((kg + q) * 128 + srow) * 8) = lp;
                }
            }
        }
        __syncthreads();
        // ---- compute ----
        const int abase = lg * 128 * 8 + (wr * 64 + lr) * 8;
        const int bbase = lg * 128 * 8 + (wc * 64 + lr) * 8;
        v8s ah[4], bh[4];
#pragma unroll
        for (int i = 0; i < 4; ++i) {
            ah[i] = *(const v8s*)(Ahs + abase + i * 16 * 8);
            bh[i] = *(const v8s*)(Bhs + bbase + i * 16 * 8);
        }
        if constexpr (SPLIT) {
            v8s al[4], bl[4];
#pragma unroll
            for (int i = 0; i < 4; ++i) {
                al[i] = *(const v8s*)(Als + abase + i * 16 * 8);
                bl[i] = *(const v8s*)(Bls + bbase + i * 16 * 8);
            }
#pragma unroll
            for (int mi = 0; mi < 4; ++mi)
#pragma unroll
                for (int nj = 0; nj < 4; ++nj) {
                    acc[mi][nj] = __builtin_amdgcn_mfma_f32_16x16x32_bf16(ah[mi], bh[nj], acc[mi][nj], 0, 0, 0);
                    acc[mi][nj] = __builtin_amdgcn_mfma_f32_16x16x32_bf16(al[mi], bh[nj], acc[mi][nj], 0, 0, 0);
                    acc[mi][nj] = __builtin_amdgcn_mfma_f32_16x16x32_bf16(ah[mi], bl[nj], acc[mi][nj], 0, 0, 0);
                }
        } else {
#pragma unroll
            for (int mi = 0; mi < 4; ++mi)
#pragma unroll
                for (int nj = 0; nj < 4; ++nj)
                    acc[mi][nj] = __builtin_amdgcn_mfma_f32_16x16x32_bf16(ah[mi], bh[nj], acc[mi][nj], 0, 0, 0);
        }
    }

    // ---- epilogue: D[row=(lane>>4)*4+r][col=lane&15] ----
#pragma unroll
    for (int mi = 0; mi < 4; ++mi) {
        const int mrow = mt * 128 + wr * 64 + mi * 16 + lg * 4;
#pragma unroll
        for (int nj = 0; nj < 4; ++nj) {
            const int ncol = nt * 128 + wc * 64 + nj * 16 + lr;
            if (ncol < p.N) {
#pragma unroll
                for (int r = 0; r < 4; ++r) {
                    const int m = mrow + r;
                    if (m < Mz) {
                        float v = acc[mi][nj][r] * p.alpha;
                        long crow;
                        if (p.grouped == 1) crow = pz + m;
                        else if (p.grouped == 2) crow = lrowz[m];
                        else crow = m;
                        long co = cOff + crow * (long)p.ldc + ncol;
                        if (p.outMode == 0) p.C[co] = v;
                        else if (p.outMode == 1) p.C[co] += v;
                        else {
                            short hi = f2bf(v);
                            p.Ch[co] = hi;
                            p.Cl[co] = f2bf(v - bf2f(hi));
                        }
                    }
                }
            }
        }
    }
}

// ---------------- small kernels ----------------
__global__ __launch_bounds__(256) void embed_kernel(const int* toks, const float* emb, float* X) {
    const int t = blockIdx.x;
    const int tok = toks[t];
    const float4* s = (const float4*)(emb + (size_t)tok * 1024);
    float4* d = (float4*)(X + (size_t)t * 1024);
    d[threadIdx.x] = s[threadIdx.x];
}

__global__ __launch_bounds__(256) void rmsnorm_split(const float* X, const float* w, short* oh, short* ol) {
    __shared__ float red[4];
    const long t = blockIdx.x;
    const float* r = X + t * 1024;
    float ss = 0.f;
    for (int j = threadIdx.x; j < 1024; j += 256) { float f = r[j]; ss += f * f; }
    ss = block_sum256(ss, red);
    const float sc = 32.f / fmaxf(sqrtf(ss), 1e-6f);
    for (int j = threadIdx.x; j < 1024; j += 256) {
        float f = r[j] * sc * w[j];
        short hi = f2bf(f);
        oh[t * 1024 + j] = hi;
        ol[t * 1024 + j] = f2bf(f - bf2f(hi));
    }
}

struct RopeF { float f[32]; };

__global__ __launch_bounds__(256) void rope_q_kernel(const float* Q, short* OH, short* OL, RopeF rf) {
    const int idx = blockIdx.x * 256 + threadIdx.x;           // B*S*H*32
    const int pp = idx & 31, h = (idx >> 5) & 15, s = (idx >> 9) & 1023, b = idx >> 19;
    const float* src = Q + ((size_t)(b * 1024 + s)) * 1024 + h * 64 + 2 * pp;
    const float x0 = src[0], x1 = src[1];
    const float ang = (float)s * rf.f[pp];
    float sn, cs; sincosf(ang, &sn, &cs);
    const float o0 = x0 * cs - x1 * sn, o1 = x0 * sn + x1 * cs;
    const size_t o = ((size_t)((b * 16 + h) * 1024 + s)) * 64 + 2 * pp;
    short h0 = f2bf(o0); OH[o] = h0; OL[o] = f2bf(o0 - bf2f(h0));
    short h1 = f2bf(o1); OH[o + 1] = h1; OL[o + 1] = f2bf(o1 - bf2f(h1));
}

__global__ __launch_bounds__(256) void rope_k_kernel(const float* Kin, float* KR, RopeF rf) {
    const int idx = blockIdx.x * 256 + threadIdx.x;           // B*S*KVH*32
    const int pp = idx & 31, kv = (idx >> 5) & 3, s = (idx >> 7) & 1023, b = idx >> 17;
    const float* src = Kin + ((size_t)(b * 1024 + s)) * 256 + kv * 64 + 2 * pp;
    const float x0 = src[0], x1 = src[1];
    const float ang = (float)s * rf.f[pp];
    float sn, cs; sincosf(ang, &sn, &cs);
    const size_t o = ((size_t)((b * 4 + kv) * 1024 + s)) * 64 + 2 * pp;
    KR[o] = x0 * cs - x1 * sn;
    KR[o + 1] = x0 * sn + x1 * cs;
}

__global__ __launch_bounds__(256) void transpose_v_kernel(const float* Vin, float* VT) {
    const int idx = blockIdx.x * 256 + threadIdx.x;           // B*S*KVH*HD
    const int d = idx & 63, kv = (idx >> 6) & 3, s = (idx >> 8) & 1023, b = idx >> 18;
    VT[((size_t)((b * 4 + kv) * 64 + d)) * 1024 + s] = Vin[idx];
}

__global__ __launch_bounds__(256) void attn_softmax(float* SC) {
    const long row = blockIdx.x;                 // z*1024 + i
    const int i = (int)(row & 1023);
    float* r = SC + row * 1024;
    __shared__ float buf[1024];
    __shared__ float red[4];
    const int n = i + 1;
    for (int j = threadIdx.x; j < 1024; j += 256) buf[j] = r[j];
    __syncthreads();
    float m = -INFINITY;
    for (int j = threadIdx.x; j < n; j += 256) m = fmaxf(m, buf[j]);
    m = block_max256(m, red);
    float s = 0.f;
    for (int j = threadIdx.x; j < n; j += 256) { float e = expf(buf[j] - m); buf[j] = e; s += e; }
    s = block_sum256(s, red);
    const float inv = 1.f / s;
    short* rh = (short*)r;
    short* rl = rh + 1024;
    __syncthreads();
    for (int j = threadIdx.x; j < 1024; j += 256) {
        float pv = (j < n) ? buf[j] * inv : 0.f;
        short hi = f2bf(pv);
        rh[j] = hi;
        rl[j] = f2bf(pv - bf2f(hi));
    }
}

__global__ __launch_bounds__(256) void router_kernel(const float* X, const float* wn, const float* rw,
                                                     float* probs, float* lse, int* cnt, int* ltok, int* lrow) {
    __shared__ float xs[1024];
    __shared__ float red[4];
    __shared__ float lg[8];
    const int t = blockIdx.x;
    const float* r = X + (size_t)t * 1024;
    for (int j = threadIdx.x; j < 1024; j += 256) xs[j] = r[j];
    __syncthreads();
    float ss = 0.f;
    for (int j = threadIdx.x; j < 1024; j += 256) ss += xs[j] * xs[j];
    ss = block_sum256(ss, red);
    const float sc = 32.f / fmaxf(sqrtf(ss), 1e-6f);
    float acc[8] = {0, 0, 0, 0, 0, 0, 0, 0};
    for (int j = threadIdx.x; j < 1024; j += 256) {
        const float xv = xs[j] * wn[j];
#pragma unroll
        for (int e = 0; e < 8; ++e) acc[e] += xv * rw[e * 1024 + j];
    }
#pragma unroll
    for (int e = 0; e < 8; ++e) {
        float s = block_sum256(acc[e], red);
        if (threadIdx.x == 0) lg[e] = s * sc;
    }
    __syncthreads();
    if (threadIdx.x == 0) {
        float m = lg[0];
        for (int e = 1; e < 8; ++e) m = fmaxf(m, lg[e]);
        float ex[8], se = 0.f;
        for (int e = 0; e < 8; ++e) { ex[e] = expf(lg[e] - m); se += ex[e]; }
        const float inv = 1.f / se;
        float pr[8];
        for (int e = 0; e < 8; ++e) { pr[e] = ex[e] * inv; probs[(size_t)t * 8 + e] = pr[e]; }
        lse[t] = m + logf(se);
        int i1 = 0;
        for (int e = 1; e < 8; ++e) if (pr[e] > pr[i1]) i1 = e;
        int i2 = (i1 == 0) ? 1 : 0;
        for (int e = 0; e < 8; ++e) if (e != i1 && pr[e] > pr[i2]) i2 = e;
        int s1 = atomicAdd(&cnt[i1], 1); ltok[i1 * 2048 + s1] = t; lrow[i1 * 2048 + s1] = 2 * t;
        int s2 = atomicAdd(&cnt[i2], 1); ltok[i2 * 2048 + s2] = t; lrow[i2 * 2048 + s2] = 2 * t + 1;
    }
}

__global__ void prefix_kernel(const int* cnt, int* pref) {
    if (threadIdx.x == 0 && blockIdx.x == 0) {
        int a = 0;
        for (int e = 0; e < 8; ++e) { pref[e] = a; a += cnt[e]; }
    }
}

__global__ __launch_bounds__(256) void silu_mul(const float* U, const float* G, short* HH, short* HL) {
    const long idx = (long)blockIdx.x * 256 + threadIdx.x;    // 4096*2048
    const float u = U[idx], g = G[idx];
    const float h = (u / (1.f + expf(-u))) * g;
    short hi = f2bf(h);
    HH[idx] = hi;
    HL[idx] = f2bf(h - bf2f(hi));
}

__global__ __launch_bounds__(256) void combine_kernel(float* X, const float* Y) {
    const int idx = blockIdx.x * 256 + threadIdx.x;           // 2048*1024
    const int t = idx >> 10, d = idx & 1023;
    X[idx] += Y[((size_t)(2 * t)) * 1024 + d] + Y[((size_t)(2 * t + 1)) * 1024 + d];
}

__global__ __launch_bounds__(256) void aux_kernel(const float* probs, const float* lse, float* auxb, int layer) {
    __shared__ float red[4];
    float sl = 0.f;
    for (int t = threadIdx.x; t < 2048; t += 256) sl += lse[t];
    sl = block_sum256(sl, red);
    float s1 = 0.f, s2 = 0.f;
    for (int i = threadIdx.x; i < 8192; i += 256) {
        const float l = probs[i] + probs[8192 + i];
        s1 += l; s2 += l * l;
    }
    s1 = block_sum256(s1, red);
    s2 = block_sum256(s2, red);
    if (threadIdx.x == 0) {
        const float ml = sl / 2048.f;
        const float mean = s1 / 8192.f;
        const float var = fmaxf((s2 - s1 * s1 / 8192.f) / 8191.f, 0.f);
        auxb[layer] = 0.001f * (ml * ml + var / (mean * mean));
    }
}

__global__ void finalize_aux(const float* auxb, float* out) {
    if (threadIdx.x == 0 && blockIdx.x == 0)
        out[(size_t)2 * 1024 * 32000] = auxb[0] + auxb[1];
}

// ---------------- launch helper ----------------
static void run_gemm(hipStream_t s, bool split, const GemmP& p, int gx, int gy, int gz) {
    dim3 g(gx, gy, gz), b(256);
    if (split) gemm_bt<true><<<g, b, 32768, s>>>(p);
    else       gemm_bt<false><<<g, b, 16384, s>>>(p);
}

extern "C" void kernel_launch(void* const* d_in, const int* in_sizes, int n_in,
                              void* d_out, int out_size, void* d_ws, size_t ws_size,
                              hipStream_t stream) {
    (void)in_sizes; (void)n_in; (void)out_size; (void)ws_size;
    const int*   tokens = (const int*)d_in[0];
    const float* tok_emb = (const float*)d_in[1];
    const float* norm1 = (const float*)d_in[2];
    const float* norm2 = (const float*)d_in[3];
    const float* wq = (const float*)d_in[4];
    const float* wk = (const float*)d_in[5];
    const float* wv = (const float*)d_in[6];
    const float* wo = (const float*)d_in[7];
    const float* rw = (const float*)d_in[8];
    const float* w1 = (const float*)d_in[9];
    const float* w2 = (const float*)d_in[10];
    const float* w3 = (const float*)d_in[11];
    const float* normf = (const float*)d_in[12];
    const float* headw = (const float*)d_in[13];
    float* out = (float*)d_out;

    char* w = (char*)d_ws;
    const size_t MB = 1024ull * 1024ull;
    float* X    = (float*)(w + 0);            // 8 MB residual fp32
    short* XNH  = (short*)(w + 8 * MB);       // 4 MB
    short* XNL  = (short*)(w + 12 * MB);      // 4 MB
    short* QRH  = (short*)(w + 16 * MB);      // 4 MB
    short* QRL  = (short*)(w + 20 * MB);      // 4 MB
    float* KR   = (float*)(w + 24 * MB);      // 2 MB (b,kvh,s,hd)
    float* VT   = (float*)(w + 26 * MB);      // 2 MB (b,kvh,hd,s)
    short* AOH  = (short*)(w + 28 * MB);      // 4 MB
    short* AOL  = (short*)(w + 32 * MB);      // 4 MB
    float* SC   = (float*)(w + 36 * MB);      // 128 MB scores / P(in-place) ; head also qtmp/ktmp/vtmp
    float* U    = (float*)(w + 164 * MB);     // 32 MB (u; later y in first 16MB)
    float* G    = (float*)(w + 196 * MB);     // 32 MB
    short* HH   = (short*)(w + 228 * MB);     // 16 MB
    short* HL   = (short*)(w + 244 * MB);     // 16 MB
    float* PROBS= (float*)(w + 260 * MB);               // 64 KB
    float* LSE  = (float*)(w + 260 * MB + 65536);       // 8 KB
    int*   CNT  = (int*)  (w + 260 * MB + 73728);
    int*   PREF = (int*)  (w + 260 * MB + 73856);
    int*   LTOK = (int*)  (w + 260 * MB + 74240);       // 64 KB
    int*   LROW = (int*)  (w + 260 * MB + 74240 + 65536);
    float* AUXB = (float*)(w + 260 * MB + 74240 + 131072);

    float* QTMP = SC;               // 2048x1024 f32
    float* KTMP = SC + 2097152;     // 2048x256
    float* VTMP = SC + 2621440;     // 2048x256

    RopeF rf;
    for (int i = 0; i < 32; ++i) {
        float t = (float)pow(10000.0, (double)(2 * i) / 64.0);
        rf.f[i] = 1.0f / t;
    }

    embed_kernel<<<2048, 256, 0, stream>>>(tokens, tok_emb, X);

    for (int l = 0; l < 2; ++l) {
        rmsnorm_split<<<2048, 256, 0, stream>>>(X, norm1 + l * 1024, XNH, XNL);

        { GemmP p = {}; p.Ah = XNH; p.Al = XNL; p.B = wq + (size_t)l * 1024 * 1024; p.C = QTMP;
          p.M = 2048; p.N = 1024; p.K = 1024; p.lda = 1024; p.ldb = 1024; p.ldc = 1024; p.alpha = 1.f;
          run_gemm(stream, true, p, 8, 16, 1); }
        { GemmP p = {}; p.Ah = XNH; p.Al = XNL; p.B = wk + (size_t)l * 256 * 1024; p.C = KTMP;
          p.M = 2048; p.N = 256; p.K = 1024; p.lda = 1024; p.ldb = 1024; p.ldc = 256; p.alpha = 1.f;
          run_gemm(stream, true, p, 2, 16, 1); }
        { GemmP p = {}; p.Ah = XNH; p.Al = XNL; p.B = wv + (size_t)l * 256 * 1024; p.C = VTMP;
          p.M = 2048; p.N = 256; p.K = 1024; p.lda = 1024; p.ldb = 1024; p.ldc = 256; p.alpha = 1.f;
          run_gemm(stream, true, p, 2, 16, 1); }

        rope_q_kernel<<<4096, 256, 0, stream>>>(QTMP, QRH, QRL, rf);
        rope_k_kernel<<<1024, 256, 0, stream>>>(KTMP, KR, rf);
        transpose_v_kernel<<<2048, 256, 0, stream>>>(VTMP, VT);

        // scores = q k^T / 8  (causal tile skip), write fp32 into SC
        { GemmP p = {}; p.Ah = QRH; p.Al = QRL; p.B = KR; p.C = SC;
          p.M = 1024; p.N = 1024; p.K = 64; p.lda = 64; p.ldb = 64; p.ldc = 1024;
          p.strideAz = 65536; p.strideBz = 65536; p.strideCz = 1048576;
          p.alpha = 0.125f; p.gqaB = 1; p.causalSkip = 1;
          run_gemm(stream, true, p, 8, 8, 32); }

        attn_softmax<<<32768, 256, 0, stream>>>(SC);

        // PV: A = P(hi|lo in-place in SC), B = VT ; out split-bf16 attno (b,s,h,hd)
        { GemmP p = {}; p.Ah = (short*)SC; p.Al = (short*)SC + 1024; p.B = VT; p.Ch = AOH; p.Cl = AOL;
          p.M = 1024; p.N = 64; p.K = 1024; p.lda = 2048; p.ldb = 1024; p.ldc = 1024;
          p.strideAz = 2097152; p.strideBz = 65536;
          p.alpha = 1.f; p.gqaB = 1; p.attnC = 1; p.causalK = 1; p.outMode = 2;
          run_gemm(stream, true, p, 1, 8, 32); }

        // x += 0.5 * attno @ wo^T
        { GemmP p = {}; p.Ah = AOH; p.Al = AOL; p.B = wo + (size_t)l * 1024 * 1024; p.C = X;
          p.M = 2048; p.N = 1024; p.K = 1024; p.lda = 1024; p.ldb = 1024; p.ldc = 1024;
          p.alpha = 0.5f; p.outMode = 1;
          run_gemm(stream, true, p, 8, 16, 1); }

        // ---- MoE ----
        rmsnorm_split<<<2048, 256, 0, stream>>>(X, norm2 + l * 1024, XNH, XNL);
        hipMemsetAsync(CNT, 0, 8 * sizeof(int), stream);
        router_kernel<<<2048, 256, 0, stream>>>(X, norm2 + l * 1024, rw + (size_t)l * 8 * 1024,
                                                PROBS, LSE, CNT, LTOK, LROW);
        prefix_kernel<<<1, 64, 0, stream>>>(CNT, PREF);

        const bool msp = (l == 0);   // layer-0 MoE feeds layer-1 router -> needs split precision
        { GemmP p = {}; p.Ah = XNH; p.Al = XNL; p.B = w1 + (size_t)l * 8 * 2048 * 1024; p.C = U;
          p.M = 2048; p.N = 2048; p.K = 1024; p.lda = 1024; p.ldb = 1024; p.ldc = 2048;
          p.strideBz = 2097152; p.alpha = 1.f; p.grouped = 1;
          p.cnt = CNT; p.prefix = PREF; p.ltok = LTOK; p.lrow = LROW;
          run_gemm(stream, msp, p, 16, 16, 8); }
        { GemmP p = {}; p.Ah = XNH; p.Al = XNL; p.B = w2 + (size_t)l * 8 * 2048 * 1024; p.C = G;
          p.M = 2048; p.N = 2048; p.K = 1024; p.lda = 1024; p.ldb = 1024; p.ldc = 2048;
          p.strideBz = 2097152; p.alpha = 1.f; p.grouped = 1;
          p.cnt = CNT; p.prefix = PREF; p.ltok = LTOK; p.lrow = LROW;
          run_gemm(stream, msp, p, 16, 16, 8); }
        silu_mul<<<32768, 256, 0, stream>>>(U, G, HH, HL);
        // y = h @ w3^T, scatter rows to U (reused as y: rows 2t+choice)
        { GemmP p = {}; p.Ah = HH; p.Al = HL; p.B = w3 + (size_t)l * 8 * 1024 * 2048; p.C = U;
          p.M = 2048; p.N = 1024; p.K = 2048; p.lda = 2048; p.ldb = 2048; p.ldc = 1024;
          p.strideBz = 2097152; p.alpha = 1.f; p.grouped = 2;
          p.cnt = CNT; p.prefix = PREF; p.ltok = LTOK; p.lrow = LROW;
          run_gemm(stream, msp, p, 8, 16, 8); }
        combine_kernel<<<8192, 256, 0, stream>>>(X, U);
        aux_kernel<<<1, 256, 0, stream>>>(PROBS, LSE, AUXB, l);
    }

    rmsnorm_split<<<2048, 256, 0, stream>>>(X, normf, XNH, XNL);
    { GemmP p = {}; p.Ah = XNH; p.B = headw; p.C = out;
      p.M = 2048; p.N = 32000; p.K = 1024; p.lda = 1024; p.ldb = 1024; p.ldc = 32000; p.alpha = 1.f;
      run_gemm(stream, false, p, 250, 16, 1); }
    finalize_aux<<<1, 1, 0, stream>>>(AUXB, out);
}

// Round 2
// 1929.703 us; speedup vs baseline: 1.1777x; 1.1777x over previous
//
#include <hip/hip_runtime.h>
#include <math.h>

#define DEV __device__ __forceinline__

using v8s = __attribute__((ext_vector_type(8))) short;   // 8 bf16 (4 VGPRs)
using v4f = __attribute__((ext_vector_type(4))) float;   // 4 fp32 acc

// ---------- bf16 helpers (RNE) ----------
DEV short f2bf(float f) {
    unsigned u = __float_as_uint(f);
    unsigned r = (u + 0x7fffu + ((u >> 16) & 1u)) >> 16;
    return (short)(unsigned short)r;
}
DEV float bf2f(short s) {
    return __uint_as_float(((unsigned)(unsigned short)s) << 16);
}

// ---------- block reductions (256 threads = 4 waves) ----------
DEV float block_sum256(float v, float* red) {
    __syncthreads();
#pragma unroll
    for (int o = 32; o >= 1; o >>= 1) v += __shfl_down(v, o, 64);
    if ((threadIdx.x & 63) == 0) red[threadIdx.x >> 6] = v;
    __syncthreads();
    return red[0] + red[1] + red[2] + red[3];
}
DEV float block_max256(float v, float* red) {
    __syncthreads();
#pragma unroll
    for (int o = 32; o >= 1; o >>= 1) v = fmaxf(v, __shfl_down(v, o, 64));
    if ((threadIdx.x & 63) == 0) red[threadIdx.x >> 6] = v;
    __syncthreads();
    return fmaxf(fmaxf(red[0], red[1]), fmaxf(red[2], red[3]));
}

// ---------------- model constants ----------------
// V=32000 D=1024 L=2 H=16 KVH=4 HD=64 E=8 FF=2048 K=2 B=2 S=1024

// ---------------- weight conversion ----------------
// src fp32 -> hi bf16 (+ optional lo bf16), chunked remap:
// dst index = (i/chunk)*dstStride + i%chunk   (units of 4 elements)
__global__ __launch_bounds__(256) void conv_kernel(const float* __restrict__ src,
                                                   short* __restrict__ hi, short* __restrict__ lo,
                                                   long total4, long chunk4, long dstStride4) {
    for (long i = (long)blockIdx.x * 256 + threadIdx.x; i < total4; i += (long)gridDim.x * 256) {
        long c = i / chunk4, r = i - c * chunk4;
        long d = c * dstStride4 + r;
        float4 f = ((const float4*)src)[i];
        short h0 = f2bf(f.x), h1 = f2bf(f.y), h2 = f2bf(f.z), h3 = f2bf(f.w);
        ((ushort4*)hi)[d] = make_ushort4((unsigned short)h0, (unsigned short)h1,
                                         (unsigned short)h2, (unsigned short)h3);
        if (lo) {
            short l0 = f2bf(f.x - bf2f(h0)), l1 = f2bf(f.y - bf2f(h1));
            short l2 = f2bf(f.z - bf2f(h2)), l3 = f2bf(f.w - bf2f(h3));
            ((ushort4*)lo)[d] = make_ushort4((unsigned short)l0, (unsigned short)l1,
                                             (unsigned short)l2, (unsigned short)l3);
        }
    }
}

// ---------------- generic GEMM ----------------
// C[M,N] = A[M,K] * B[N,K]^T, all operands bf16 hi(+lo) planes, fp32 accum.
struct GemmP {
    const short* Ah; const short* Al;
    const short* Bh; const short* Bl;
    float* C; short* Ch; short* Cl;
    const int* cnt; const int* prefix; const int* ltok; const int* lrow;
    long strideAz, strideBz, strideCz;
    int M, N, K, lda, ldb, ldc;
    float alpha;
    int outMode;    // 0 store f32, 1 C += alpha*acc, 2 split-bf16 store (Ch/Cl)
    int gqaB;       // B z-offset uses GQA mapping (z=b*16+h -> b*4+h/4)
    int attnC;      // C offset = b*S*D + h*HD (attn output layout)
    int grouped;    // 0 none; 1 gather A rows by token list, C rows at prefix; 2 A rows at prefix, C rows scattered by lrow
    int causalSkip; // skip blocks with nt > mt
    int causalK;    // limit K loop to (mt+1)*128
    int ntiles, S, G; // group decode: group=(nt,z), member=mt; S=mtiles, G=ntiles*zdim
};

template<bool SPLIT>
__global__ __launch_bounds__(256) void gemm_bt(GemmP p) {
    // ---- XCD-group decode: all members (mt) of one B-panel group on one XCD ----
    const int lid = blockIdx.x;
    const int xcd = lid & 7, sI = lid >> 3;
    const int gi = xcd + 8 * (sI / p.S);
    if (gi >= p.G) return;
    const int mt = sI % p.S;
    const int nt = gi % p.ntiles;
    const int z  = gi / p.ntiles;
    if (p.causalSkip && nt > mt) return;

    const int tid = threadIdx.x;

    int Mz = p.M;
    const int* ltokz = nullptr; const int* lrowz = nullptr; int pz = 0;
    if (p.grouped) {
        Mz = p.cnt[z]; pz = p.prefix[z];
        ltokz = p.ltok + z * 2048; lrowz = p.lrow + z * 2048;
    }
    if (mt * 128 >= Mz) return;

    long aOff = (long)z * p.strideAz;
    long bOff, cOff;
    if (p.gqaB) { int b = z >> 4, h = z & 15; bOff = (long)(b * 4 + (h >> 2)) * p.strideBz; }
    else bOff = (long)z * p.strideBz;
    if (p.attnC) { int b = z >> 4, h = z & 15; cOff = (long)b * 1048576 + h * 64; }
    else cOff = (long)z * p.strideCz;

    extern __shared__ char smem[];
    short* Ahs = (short*)smem;          // [4][128][8]
    short* Bhs = Ahs + 4096;
    short* Als = Bhs + 4096;            // SPLIT only
    short* Bls = Als + 4096;

    const int lane = tid & 63, w = tid >> 6;
    const int lr = lane & 15, lg = lane >> 4;
    const int wr = w >> 1, wc = w & 1;

    v4f acc[4][4];
#pragma unroll
    for (int i = 0; i < 4; ++i)
#pragma unroll
        for (int j = 0; j < 4; ++j) { acc[i][j][0] = 0.f; acc[i][j][1] = 0.f; acc[i][j][2] = 0.f; acc[i][j][3] = 0.f; }

    const int srow = tid >> 1;          // 0..127
    const int sseg = tid & 1;           // which 16-elem half of BK=32
    const int kg = sseg * 2;

    int am = mt * 128 + srow; if (am >= Mz) am = Mz - 1;
    long arowoff;
    if (p.grouped == 1)      arowoff = (long)ltokz[am] * p.lda;
    else if (p.grouped == 2) arowoff = (long)(pz + am) * p.lda;
    else                     arowoff = aOff + (long)am * p.lda;
    int bn = nt * 128 + srow; if (bn >= p.N) bn = p.N - 1;
    const long browoff = bOff + (long)bn * p.ldb;

    const short* aH = p.Ah + arowoff + sseg * 16;
    const short* bH = p.Bh + browoff + sseg * 16;
    const short* aL = SPLIT ? p.Al + arowoff + sseg * 16 : nullptr;
    const short* bL = SPLIT ? p.Bl + browoff + sseg * 16 : nullptr;
    short* dA0 = Ahs + (kg * 128 + srow) * 8; short* dA1 = dA0 + 1024;
    short* dB0 = Bhs + (kg * 128 + srow) * 8; short* dB1 = dB0 + 1024;
    short* dA0l = Als + (kg * 128 + srow) * 8; short* dA1l = dA0l + 1024;
    short* dB0l = Bls + (kg * 128 + srow) * 8; short* dB1l = dB0l + 1024;

    const int kEnd = p.causalK ? min(p.K, (mt + 1) * 128) : p.K;

    for (int k0 = 0; k0 < kEnd; k0 += 32) {
        __syncthreads();
        *(uint4*)dA0 = *(const uint4*)(aH + k0);
        *(uint4*)dA1 = *(const uint4*)(aH + k0 + 8);
        *(uint4*)dB0 = *(const uint4*)(bH + k0);
        *(uint4*)dB1 = *(const uint4*)(bH + k0 + 8);
        if (SPLIT) {
            *(uint4*)dA0l = *(const uint4*)(aL + k0);
            *(uint4*)dA1l = *(const uint4*)(aL + k0 + 8);
            *(uint4*)dB0l = *(const uint4*)(bL + k0);
            *(uint4*)dB1l = *(const uint4*)(bL + k0 + 8);
        }
        __syncthreads();
        const int abase = lg * 1024 + (wr * 64 + lr) * 8;
        const int bbase = lg * 1024 + (wc * 64 + lr) * 8;
        v8s ah[4], bh[4];
#pragma unroll
        for (int i = 0; i < 4; ++i) {
            ah[i] = *(const v8s*)(Ahs + abase + i * 128);
            bh[i] = *(const v8s*)(Bhs + bbase + i * 128);
        }
        if constexpr (SPLIT) {
            v8s al[4], bl[4];
#pragma unroll
            for (int i = 0; i < 4; ++i) {
                al[i] = *(const v8s*)(Als + abase + i * 128);
                bl[i] = *(const v8s*)(Bls + bbase + i * 128);
            }
#pragma unroll
            for (int mi = 0; mi < 4; ++mi)
#pragma unroll
                for (int nj = 0; nj < 4; ++nj) {
                    acc[mi][nj] = __builtin_amdgcn_mfma_f32_16x16x32_bf16(ah[mi], bh[nj], acc[mi][nj], 0, 0, 0);
                    acc[mi][nj] = __builtin_amdgcn_mfma_f32_16x16x32_bf16(al[mi], bh[nj], acc[mi][nj], 0, 0, 0);
                    acc[mi][nj] = __builtin_amdgcn_mfma_f32_16x16x32_bf16(ah[mi], bl[nj], acc[mi][nj], 0, 0, 0);
                }
        } else {
#pragma unroll
            for (int mi = 0; mi < 4; ++mi)
#pragma unroll
                for (int nj = 0; nj < 4; ++nj)
                    acc[mi][nj] = __builtin_amdgcn_mfma_f32_16x16x32_bf16(ah[mi], bh[nj], acc[mi][nj], 0, 0, 0);
        }
    }

    // ---- epilogue: D[row=(lane>>4)*4+r][col=lane&15] ----
#pragma unroll
    for (int mi = 0; mi < 4; ++mi) {
        const int mrow = mt * 128 + wr * 64 + mi * 16 + lg * 4;
#pragma unroll
        for (int nj = 0; nj < 4; ++nj) {
            const int ncol = nt * 128 + wc * 64 + nj * 16 + lr;
            if (ncol < p.N) {
#pragma unroll
                for (int r = 0; r < 4; ++r) {
                    const int m = mrow + r;
                    if (m < Mz) {
                        float v = acc[mi][nj][r] * p.alpha;
                        long crow;
                        if (p.grouped == 1) crow = pz + m;
                        else if (p.grouped == 2) crow = lrowz[m];
                        else crow = m;
                        long co = cOff + crow * (long)p.ldc + ncol;
                        if (p.outMode == 0) p.C[co] = v;
                        else if (p.outMode == 1) p.C[co] += v;
                        else {
                            short hi = f2bf(v);
                            p.Ch[co] = hi;
                            p.Cl[co] = f2bf(v - bf2f(hi));
                        }
                    }
                }
            }
        }
    }
}

// ---------------- small kernels ----------------
__global__ __launch_bounds__(256) void embed_kernel(const int* toks, const float* emb, float* X) {
    const int t = blockIdx.x;
    const int tok = toks[t];
    const float4* s = (const float4*)(emb + (size_t)tok * 1024);
    float4* d = (float4*)(X + (size_t)t * 1024);
    d[threadIdx.x] = s[threadIdx.x];
}

__global__ __launch_bounds__(256) void rmsnorm_split(const float* X, const float* w, short* oh, short* ol) {
    __shared__ float red[4];
    const long t = blockIdx.x;
    const float* r = X + t * 1024;
    float ss = 0.f;
    for (int j = threadIdx.x; j < 1024; j += 256) { float f = r[j]; ss += f * f; }
    ss = block_sum256(ss, red);
    const float sc = 32.f / fmaxf(sqrtf(ss), 1e-6f);
    for (int j = threadIdx.x; j < 1024; j += 256) {
        float f = r[j] * sc * w[j];
        short hi = f2bf(f);
        oh[t * 1024 + j] = hi;
        ol[t * 1024 + j] = f2bf(f - bf2f(hi));
    }
}

struct RopeF { float f[32]; };

__global__ __launch_bounds__(256) void rope_q_kernel(const float* QKV, short* OH, short* OL, RopeF rf) {
    const int idx = blockIdx.x * 256 + threadIdx.x;           // B*S*H*32
    const int pp = idx & 31, h = (idx >> 5) & 15, s = (idx >> 9) & 1023, b = idx >> 19;
    const float* src = QKV + ((size_t)(b * 1024 + s)) * 1536 + h * 64 + 2 * pp;
    const float x0 = src[0], x1 = src[1];
    const float ang = (float)s * rf.f[pp];
    float sn, cs; sincosf(ang, &sn, &cs);
    const float o0 = x0 * cs - x1 * sn, o1 = x0 * sn + x1 * cs;
    const size_t o = ((size_t)((b * 16 + h) * 1024 + s)) * 64 + 2 * pp;
    short h0 = f2bf(o0); OH[o] = h0; OL[o] = f2bf(o0 - bf2f(h0));
    short h1 = f2bf(o1); OH[o + 1] = h1; OL[o + 1] = f2bf(o1 - bf2f(h1));
}

__global__ __launch_bounds__(256) void rope_k_kernel(const float* QKV, short* KH, short* KL, RopeF rf) {
    const int idx = blockIdx.x * 256 + threadIdx.x;           // B*S*KVH*32
    const int pp = idx & 31, kv = (idx >> 5) & 3, s = (idx >> 7) & 1023, b = idx >> 17;
    const float* src = QKV + ((size_t)(b * 1024 + s)) * 1536 + 1024 + kv * 64 + 2 * pp;
    const float x0 = src[0], x1 = src[1];
    const float ang = (float)s * rf.f[pp];
    float sn, cs; sincosf(ang, &sn, &cs);
    const float o0 = x0 * cs - x1 * sn, o1 = x0 * sn + x1 * cs;
    const size_t o = ((size_t)((b * 4 + kv) * 1024 + s)) * 64 + 2 * pp;
    short h0 = f2bf(o0); KH[o] = h0; KL[o] = f2bf(o0 - bf2f(h0));
    short h1 = f2bf(o1); KH[o + 1] = h1; KL[o + 1] = f2bf(o1 - bf2f(h1));
}

__global__ __launch_bounds__(256) void transpose_v_kernel(const float* QKV, short* VH, short* VL) {
    const int idx = blockIdx.x * 256 + threadIdx.x;           // B*S*KVH*HD
    const int d = idx & 63, kv = (idx >> 6) & 3, s = (idx >> 8) & 1023, b = idx >> 18;
    const float f = QKV[((size_t)(b * 1024 + s)) * 1536 + 1280 + kv * 64 + d];
    const size_t o = ((size_t)((b * 4 + kv) * 64 + d)) * 1024 + s;
    short hi = f2bf(f);
    VH[o] = hi; VL[o] = f2bf(f - bf2f(hi));
}

__global__ __launch_bounds__(256) void attn_softmax(float* SC) {
    const long row = blockIdx.x;                 // z*1024 + i
    const int i = (int)(row & 1023);
    float* r = SC + row * 1024;
    __shared__ float buf[1024];
    __shared__ float red[4];
    const int n = i + 1;
    for (int j = threadIdx.x; j < 1024; j += 256) buf[j] = r[j];
    __syncthreads();
    float m = -INFINITY;
    for (int j = threadIdx.x; j < n; j += 256) m = fmaxf(m, buf[j]);
    m = block_max256(m, red);
    float s = 0.f;
    for (int j = threadIdx.x; j < n; j += 256) { float e = expf(buf[j] - m); buf[j] = e; s += e; }
    s = block_sum256(s, red);
    const float inv = 1.f / s;
    short* rh = (short*)r;
    short* rl = rh + 1024;
    __syncthreads();
    for (int j = threadIdx.x; j < 1024; j += 256) {
        float pv = (j < n) ? buf[j] * inv : 0.f;
        short hi = f2bf(pv);
        rh[j] = hi;
        rl[j] = f2bf(pv - bf2f(hi));
    }
}

__global__ __launch_bounds__(256) void router_kernel(const float* X, const float* wn, const float* rw,
                                                     float* probs, float* lse, int* cnt, int* ltok, int* lrow) {
    __shared__ float xs[1024];
    __shared__ float red[4];
    __shared__ float lg[8];
    const int t = blockIdx.x;
    const float* r = X + (size_t)t * 1024;
    for (int j = threadIdx.x; j < 1024; j += 256) xs[j] = r[j];
    __syncthreads();
    float ss = 0.f;
    for (int j = threadIdx.x; j < 1024; j += 256) ss += xs[j] * xs[j];
    ss = block_sum256(ss, red);
    const float sc = 32.f / fmaxf(sqrtf(ss), 1e-6f);
    float acc[8] = {0, 0, 0, 0, 0, 0, 0, 0};
    for (int j = threadIdx.x; j < 1024; j += 256) {
        const float xv = xs[j] * wn[j];
#pragma unroll
        for (int e = 0; e < 8; ++e) acc[e] += xv * rw[e * 1024 + j];
    }
#pragma unroll
    for (int e = 0; e < 8; ++e) {
        float s = block_sum256(acc[e], red);
        if (threadIdx.x == 0) lg[e] = s * sc;
    }
    __syncthreads();
    if (threadIdx.x == 0) {
        float m = lg[0];
        for (int e = 1; e < 8; ++e) m = fmaxf(m, lg[e]);
        float ex[8], se = 0.f;
        for (int e = 0; e < 8; ++e) { ex[e] = expf(lg[e] - m); se += ex[e]; }
        const float inv = 1.f / se;
        float pr[8];
        for (int e = 0; e < 8; ++e) { pr[e] = ex[e] * inv; probs[(size_t)t * 8 + e] = pr[e]; }
        lse[t] = m + logf(se);
        int i1 = 0;
        for (int e = 1; e < 8; ++e) if (pr[e] > pr[i1]) i1 = e;
        int i2 = (i1 == 0) ? 1 : 0;
        for (int e = 0; e < 8; ++e) if (e != i1 && pr[e] > pr[i2]) i2 = e;
        int s1 = atomicAdd(&cnt[i1], 1); ltok[i1 * 2048 + s1] = t; lrow[i1 * 2048 + s1] = 2 * t;
        int s2 = atomicAdd(&cnt[i2], 1); ltok[i2 * 2048 + s2] = t; lrow[i2 * 2048 + s2] = 2 * t + 1;
    }
}

__global__ void prefix_kernel(const int* cnt, int* pref) {
    if (threadIdx.x == 0 && blockIdx.x == 0) {
        int a = 0;
        for (int e = 0; e < 8; ++e) { pref[e] = a; a += cnt[e]; }
    }
}

// U layout: [row][4096] with u in cols 0..2047, g in cols 2048..4095
__global__ __launch_bounds__(256) void silu_mul(const float* U, short* HH, short* HL) {
    const long i4 = (long)blockIdx.x * 256 + threadIdx.x;     // 4096*2048/4 = 2M
    const int f4 = (int)(i4 & 511), row = (int)(i4 >> 9);
    const float4 u = *(const float4*)(U + ((long)row << 12) + (f4 << 2));
    const float4 g = *(const float4*)(U + ((long)row << 12) + 2048 + (f4 << 2));
    float h[4];
    h[0] = (u.x / (1.f + expf(-u.x))) * g.x;
    h[1] = (u.y / (1.f + expf(-u.y))) * g.y;
    h[2] = (u.z / (1.f + expf(-u.z))) * g.z;
    h[3] = (u.w / (1.f + expf(-u.w))) * g.w;
    const long o = (long)row * 2048 + (f4 << 2);
    short h0 = f2bf(h[0]), h1 = f2bf(h[1]), h2 = f2bf(h[2]), h3 = f2bf(h[3]);
    *(ushort4*)(HH + o) = make_ushort4((unsigned short)h0, (unsigned short)h1,
                                       (unsigned short)h2, (unsigned short)h3);
    short l0 = f2bf(h[0] - bf2f(h0)), l1 = f2bf(h[1] - bf2f(h1));
    short l2 = f2bf(h[2] - bf2f(h2)), l3 = f2bf(h[3] - bf2f(h3));
    *(ushort4*)(HL + o) = make_ushort4((unsigned short)l0, (unsigned short)l1,
                                       (unsigned short)l2, (unsigned short)l3);
}

__global__ __launch_bounds__(256) void combine_kernel(float* X, const float* Y) {
    const int i4 = blockIdx.x * 256 + threadIdx.x;            // 2048*1024/4
    const int t = i4 >> 8, d4 = i4 & 255;
    float4 x = ((float4*)X)[i4];
    const float4 a = ((const float4*)Y)[(size_t)(2 * t) * 256 + d4];
    const float4 b = ((const float4*)Y)[(size_t)(2 * t + 1) * 256 + d4];
    x.x += a.x + b.x; x.y += a.y + b.y; x.z += a.z + b.z; x.w += a.w + b.w;
    ((float4*)X)[i4] = x;
}

__global__ __launch_bounds__(256) void aux_kernel(const float* probs, const float* lse, float* auxb, int layer) {
    __shared__ float red[4];
    float sl = 0.f;
    for (int t = threadIdx.x; t < 2048; t += 256) sl += lse[t];
    sl = block_sum256(sl, red);
    float s1 = 0.f, s2 = 0.f;
    for (int i = threadIdx.x; i < 8192; i += 256) {
        const float l = probs[i] + probs[8192 + i];
        s1 += l; s2 += l * l;
    }
    s1 = block_sum256(s1, red);
    s2 = block_sum256(s2, red);
    if (threadIdx.x == 0) {
        const float ml = sl / 2048.f;
        const float mean = s1 / 8192.f;
        const float var = fmaxf((s2 - s1 * s1 / 8192.f) / 8191.f, 0.f);
        auxb[layer] = 0.001f * (ml * ml + var / (mean * mean));
    }
}

__global__ void finalize_aux(const float* auxb, float* out) {
    if (threadIdx.x == 0 && blockIdx.x == 0)
        out[(size_t)2 * 1024 * 32000] = auxb[0] + auxb[1];
}

// ---------------- launch helpers ----------------
static void run_gemm(hipStream_t s, bool split, GemmP& p, int ntiles, int mtiles, int zdim) {
    p.ntiles = ntiles; p.S = mtiles;
    p.G = ntiles * zdim;
    int Gp = (p.G + 7) & ~7;
    long nb = (long)Gp * mtiles;
    dim3 g((unsigned)nb, 1, 1), b(256);
    if (split) gemm_bt<true><<<g, b, 32768, s>>>(p);
    else       gemm_bt<false><<<g, b, 16384, s>>>(p);
}

static void run_conv(hipStream_t s, const float* src, short* hi, short* lo,
                     long total, long chunk, long dstStride) {
    long t4 = total / 4;
    long nb = (t4 + 255) / 256; if (nb > 2048) nb = 2048;
    conv_kernel<<<(unsigned)nb, 256, 0, s>>>(src, hi, lo, t4, chunk / 4, dstStride / 4);
}

extern "C" void kernel_launch(void* const* d_in, const int* in_sizes, int n_in,
                              void* d_out, int out_size, void* d_ws, size_t ws_size,
                              hipStream_t stream) {
    (void)in_sizes; (void)n_in; (void)out_size; (void)ws_size;
    const int*   tokens = (const int*)d_in[0];
    const float* tok_emb = (const float*)d_in[1];
    const float* norm1 = (const float*)d_in[2];
    const float* norm2 = (const float*)d_in[3];
    const float* wq = (const float*)d_in[4];
    const float* wk = (const float*)d_in[5];
    const float* wv = (const float*)d_in[6];
    const float* wo = (const float*)d_in[7];
    const float* rw = (const float*)d_in[8];
    const float* w1 = (const float*)d_in[9];
    const float* w2 = (const float*)d_in[10];
    const float* w3 = (const float*)d_in[11];
    const float* normf = (const float*)d_in[12];
    const float* headw = (const float*)d_in[13];
    float* out = (float*)d_out;

    char* w = (char*)d_ws;
    const size_t MB = 1024ull * 1024ull;
    float* X    = (float*)(w + 0);            // 8 MB residual fp32
    short* XNH  = (short*)(w + 8 * MB);
    short* XNL  = (short*)(w + 12 * MB);
    short* AOH  = (short*)(w + 16 * MB);
    short* AOL  = (short*)(w + 20 * MB);
    short* QRH  = (short*)(w + 24 * MB);
    short* QRL  = (short*)(w + 28 * MB);
    short* KRH  = (short*)(w + 32 * MB);      // 1 MB each
    short* KRL  = (short*)(w + 33 * MB);
    short* VTH  = (short*)(w + 34 * MB);
    short* VTL  = (short*)(w + 35 * MB);
    // BIG union region 36..164 MB:
    float* QKV  = (float*)(w + 36 * MB);      // 12 MB (dead before SC written)
    float* SC   = (float*)(w + 36 * MB);      // 128 MB scores / P planes in place
    float* U    = (float*)(w + 36 * MB);      // 64 MB [4096][4096] u|g
    short* HH   = (short*)(w + 100 * MB);     // 16 MB
    short* HL   = (short*)(w + 116 * MB);     // 16 MB
    float* Y    = (float*)(w + 132 * MB);     // 16 MB
    float* PROBS= (float*)(w + 164 * MB);               // 64 KB
    float* LSE  = (float*)(w + 164 * MB + 65536);       // 8 KB
    int*   CNT  = (int*)  (w + 164 * MB + 73728);
    int*   PREF = (int*)  (w + 164 * MB + 73856);
    int*   LTOK = (int*)  (w + 164 * MB + 74240);       // 64 KB
    int*   LROW = (int*)  (w + 164 * MB + 74240 + 65536);
    float* AUXB = (float*)(w + 164 * MB + 74240 + 131072);
    // converted weights:
    short* WQKVH = (short*)(w + 166 * MB);    // 6 MB  [l][1536][1024]
    short* WQKVL = (short*)(w + 172 * MB);    // 6 MB
    short* WOH   = (short*)(w + 178 * MB);    // 4 MB
    short* WOL   = (short*)(w + 182 * MB);    // 4 MB
    short* W12H  = (short*)(w + 186 * MB);    // 64 MB per-layer [e][4096][1024]
    short* W12L  = (short*)(w + 250 * MB);    // 64 MB (layer 0 only)
    short* W3H   = (short*)(w + 314 * MB);    // 32 MB per-layer [e][1024][2048]
    short* W3L   = (short*)(w + 346 * MB);    // 32 MB (layer 0 only)
    short* HDH   = (short*)(w + 378 * MB);    // 65.5 MB
    // total ~444 MB

    RopeF rf;
    for (int i = 0; i < 32; ++i) {
        float t = (float)pow(10000.0, (double)(2 * i) / 64.0);
        rf.f[i] = 1.0f / t;
    }

    // ---- weight conversion (once per launch) ----
    for (int l = 0; l < 2; ++l) {
        long qo = (long)l * 1572864;
        run_conv(stream, wq + (long)l * 1048576, WQKVH + qo,           WQKVL + qo,           1048576, 1048576, 1048576);
        run_conv(stream, wk + (long)l * 262144,  WQKVH + qo + 1048576, WQKVL + qo + 1048576, 262144,  262144,  262144);
        run_conv(stream, wv + (long)l * 262144,  WQKVH + qo + 1310720, WQKVL + qo + 1310720, 262144,  262144,  262144);
    }
    run_conv(stream, wo, WOH, WOL, 2097152, 2097152, 2097152);
    run_conv(stream, headw, HDH, nullptr, 32768000, 32768000, 32768000);

    embed_kernel<<<2048, 256, 0, stream>>>(tokens, tok_emb, X);

    for (int l = 0; l < 2; ++l) {
        const bool msp = (l == 0);   // layer-0 MoE feeds layer-1 router -> split precision
        // per-layer MoE weight conversion: w1|w2 interleaved per expert, w3 contiguous
        run_conv(stream, w1 + (long)l * 16777216, W12H,           msp ? W12L : nullptr,           16777216, 2097152, 4194304);
        run_conv(stream, w2 + (long)l * 16777216, W12H + 2097152, msp ? W12L + 2097152 : nullptr, 16777216, 2097152, 4194304);
        run_conv(stream, w3 + (long)l * 16777216, W3H,            msp ? W3L : nullptr,            16777216, 16777216, 16777216);

        rmsnorm_split<<<2048, 256, 0, stream>>>(X, norm1 + l * 1024, XNH, XNL);

        // fused QKV: [2048][1536] fp32
        { GemmP p = {}; p.Ah = XNH; p.Al = XNL; p.Bh = WQKVH + (long)l * 1572864; p.Bl = WQKVL + (long)l * 1572864;
          p.C = QKV; p.M = 2048; p.N = 1536; p.K = 1024; p.lda = 1024; p.ldb = 1024; p.ldc = 1536; p.alpha = 1.f;
          run_gemm(stream, true, p, 12, 16, 1); }

        rope_q_kernel<<<4096, 256, 0, stream>>>(QKV, QRH, QRL, rf);
        rope_k_kernel<<<1024, 256, 0, stream>>>(QKV, KRH, KRL, rf);
        transpose_v_kernel<<<2048, 256, 0, stream>>>(QKV, VTH, VTL);

        // scores = q k^T / 8  (causal tile skip), fp32 into SC
        { GemmP p = {}; p.Ah = QRH; p.Al = QRL; p.Bh = KRH; p.Bl = KRL; p.C = SC;
          p.M = 1024; p.N = 1024; p.K = 64; p.lda = 64; p.ldb = 64; p.ldc = 1024;
          p.strideAz = 65536; p.strideBz = 65536; p.strideCz = 1048576;
          p.alpha = 0.125f; p.gqaB = 1; p.causalSkip = 1;
          run_gemm(stream, true, p, 8, 8, 32); }

        attn_softmax<<<32768, 256, 0, stream>>>(SC);

        // PV: A = P(hi|lo in-place), B = V^T planes; out split-bf16 (b,s,h,hd)
        { GemmP p = {}; p.Ah = (short*)SC; p.Al = (short*)SC + 1024; p.Bh = VTH; p.Bl = VTL; p.Ch = AOH; p.Cl = AOL;
          p.M = 1024; p.N = 64; p.K = 1024; p.lda = 2048; p.ldb = 1024; p.ldc = 1024;
          p.strideAz = 2097152; p.strideBz = 65536;
          p.alpha = 1.f; p.gqaB = 1; p.attnC = 1; p.causalK = 1; p.outMode = 2;
          run_gemm(stream, true, p, 1, 8, 32); }

        // x += 0.5 * attno @ wo^T
        { GemmP p = {}; p.Ah = AOH; p.Al = AOL; p.Bh = WOH + (long)l * 1048576; p.Bl = WOL + (long)l * 1048576; p.C = X;
          p.M = 2048; p.N = 1024; p.K = 1024; p.lda = 1024; p.ldb = 1024; p.ldc = 1024;
          p.alpha = 0.5f; p.outMode = 1;
          run_gemm(stream, true, p, 8, 16, 1); }

        // ---- MoE ----
        rmsnorm_split<<<2048, 256, 0, stream>>>(X, norm2 + l * 1024, XNH, XNL);
        hipMemsetAsync(CNT, 0, 8 * sizeof(int), stream);
        router_kernel<<<2048, 256, 0, stream>>>(X, norm2 + l * 1024, rw + (size_t)l * 8 * 1024,
                                                PROBS, LSE, CNT, LTOK, LROW);
        prefix_kernel<<<1, 64, 0, stream>>>(CNT, PREF);

        // fused u|g: [rows][4096]
        { GemmP p = {}; p.Ah = XNH; p.Al = XNL; p.Bh = W12H; p.Bl = W12L; p.C = U;
          p.M = 2048; p.N = 4096; p.K = 1024; p.lda = 1024; p.ldb = 1024; p.ldc = 4096;
          p.strideBz = 4194304; p.alpha = 1.f; p.grouped = 1;
          p.cnt = CNT; p.prefix = PREF; p.ltok = LTOK; p.lrow = LROW;
          run_gemm(stream, msp, p, 32, 16, 8); }
        silu_mul<<<8192, 256, 0, stream>>>(U, HH, HL);
        // y = h @ w3^T, scatter rows by lrow into Y
        { GemmP p = {}; p.Ah = HH; p.Al = HL; p.Bh = W3H; p.Bl = W3L; p.C = Y;
          p.M = 2048; p.N = 1024; p.K = 2048; p.lda = 2048; p.ldb = 2048; p.ldc = 1024;
          p.strideBz = 2097152; p.alpha = 1.f; p.grouped = 2;
          p.cnt = CNT; p.prefix = PREF; p.ltok = LTOK; p.lrow = LROW;
          run_gemm(stream, msp, p, 8, 16, 8); }
        combine_kernel<<<2048, 256, 0, stream>>>(X, Y);
        aux_kernel<<<1, 256, 0, stream>>>(PROBS, LSE, AUXB, l);
    }

    rmsnorm_split<<<2048, 256, 0, stream>>>(X, normf, XNH, XNL);
    { GemmP p = {}; p.Ah = XNH; p.Bh = HDH; p.C = out;
      p.M = 2048; p.N = 32000; p.K = 1024; p.lda = 1024; p.ldb = 1024; p.ldc = 32000; p.alpha = 1.f;
      run_gemm(stream, false, p, 250, 16, 1); }
    finalize_aux<<<1, 1, 0, stream>>>(AUXB, out);
}